// Round 9
// baseline (44.655 us; speedup 1.0000x reference)
//
#include <hip/hip_runtime.h>

#define HADN 4096
#define NFEAT 2048
#define ROWS_PER_IT 2
#define ITERS 4
#define INV2PI 0.15915494309189535f

typedef float floatx4 __attribute__((ext_vector_type(4)));
typedef const __attribute__((address_space(1))) void* gas_cptr;
typedef __attribute__((address_space(3))) void* las_ptr;

// Async global->LDS DMA, 16B per lane. Address-space casts via integer
// round-trip. LDS dest must be wave-uniform base + lane*16 (ours is).
__device__ __forceinline__ void gload_lds16(const float* g, float* l) {
  __builtin_amdgcn_global_load_lds(
      (gas_cptr)(unsigned long long)g,
      (las_ptr)(unsigned)(unsigned long long)l, 16, 0, 0);
}

// out-bit <- in-axis mapping of one reference "fwht" (derived by axis tracking):
// bit0<-a6, bit1<-H(a3), bit2<-a7, bit3<-a0, bit4<-a8, bit5<-H(a4),
// bit6<-a9, bit7<-a2, bit8<-a10, bit9<-H(a5), bit10<-a11, bit11<-H(a1)
__device__ __forceinline__ int pi_map(int q) {
  return  (((q >> 3) & 1))
        | (((q >> 11) & 1) << 1)
        | (((q >> 7) & 1) << 2)
        | (((q >> 1) & 1) << 3)
        | (((q >> 5) & 1) << 4)
        | (((q >> 9) & 1) << 5)
        | (((q >> 0) & 1) << 6)
        | (((q >> 2) & 1) << 7)
        | (((q >> 4) & 1) << 8)
        | (((q >> 6) & 1) << 9)
        | (((q >> 8) & 1) << 10)
        | (((q >> 10) & 1) << 11);
}

__device__ __forceinline__ int pi_inv_map(int p) {
  return  (((p >> 6) & 1))
        | (((p >> 3) & 1) << 1)
        | (((p >> 7) & 1) << 2)
        | (((p >> 0) & 1) << 3)
        | (((p >> 8) & 1) << 4)
        | (((p >> 4) & 1) << 5)
        | (((p >> 9) & 1) << 6)
        | (((p >> 2) & 1) << 7)
        | (((p >> 10) & 1) << 8)
        | (((p >> 5) & 1) << 9)
        | (((p >> 11) & 1) << 10)
        | (((p >> 1) & 1) << 11);
}

// LDS bank swizzle: XOR bits {6,7,8}^{9,10,11} into bits {2,3,4}.
// Intra-128B-line permutation -> pre-swizzling the GLOBAL source keeps
// full-line coalescing per DMA instruction while LDS dest stays linear.
__device__ __forceinline__ int swz(int p) {
  return p ^ ((((p >> 6) ^ (p >> 9)) & 7) << 2);
}

template <int BIT>
__device__ __forceinline__ void bfly(float* r) {
#pragma unroll
  for (int e = 0; e < 16; ++e) {
    if ((e & BIT) == 0) {
      const int f = e | BIT;
      const float a = r[e], b = r[f];
      r[e] = a + b;
      r[f] = a - b;
    }
  }
}

// Cross-lane butterfly via DPP quad-perm (VALU, not DS pipe).
// CTRL=0xB1 -> lane^1, CTRL=0x4E -> lane^2.
template <int CTRL>
__device__ __forceinline__ void dpp_bfly(float* r, bool upper) {
  const unsigned sm = upper ? 0x80000000u : 0u;
#pragma unroll
  for (int e = 0; e < 16; ++e) {
    const int pv = __builtin_amdgcn_update_dpp(
        0, __float_as_int(r[e]), CTRL, 0xF, 0xF, true);
    r[e] = __int_as_float(pv) + __int_as_float(__float_as_int(r[e]) ^ sm);
  }
}

// Single fused kernel: each block computes the (tiny) setup products itself
// (sign masks via ballot into LDS; its table quad into registers), then
// processes 4 row-pairs. No setup kernel, no graph dependency gap.
__global__ __launch_bounds__(512) void srf_all(
    const float* __restrict__ x, const float* __restrict__ D1,
    const float* __restrict__ D2, const float* __restrict__ D3,
    const int* __restrict__ perm, const float* __restrict__ bias,
    float* __restrict__ out) {
  __shared__ float lds[ROWS_PER_IT][HADN];  // 32 KiB
  __shared__ unsigned sgn[2][HADN / 32];    // 1 KiB: [0]=D1 signs, [1]=D2 signs
  const int tid = threadIdx.x;
  const int rr = tid >> 8;                  // which of the pair's 2 rows
  const int t256 = tid & 255;
  const int l = tid & 63;
  const int w = (tid >> 6) & 3;             // wave-in-row -> p-bits {10,11}
  const int lane = tid & 63;
  const long row0 = (long)blockIdx.x * (ROWS_PER_IT * ITERS);
  const int base = (((l >> 2) & 1) << 2) | ((l & 1) << 5) | (((l >> 3) & 1) << 6)
                 | (((l >> 4) & 1) << 7) | (((l >> 1) & 1) << 8)
                 | (((l >> 5) & 1) << 9) | (w << 10);

  // Issue first row-pair DMA immediately; its latency hides under setup.
  {
    const float* xr = x + (row0 + rr) * HADN;
#pragma unroll
    for (int k = 0; k < 4; ++k) {
      const int p = (k * 256 + t256) * 4;
      gload_lds16(xr + swz(p), &lds[rr][p]);
    }
  }

  // Sign masks: 4096 bits each via 8 ballot rounds (512 threads/round).
  // Wave wv covers indices [j*512 + wv*64, +64); lanes 0/32 write words.
#pragma unroll
  for (int j = 0; j < 8; ++j) {
    const int idx = j * 512 + tid;
    const bool b1 = (__float_as_uint(D1[idx]) >> 31) != 0;
    const bool b2 = (__float_as_uint(D2[pi_inv_map(idx)]) >> 31) != 0;
    const unsigned long long m1 = __ballot(b1);
    const unsigned long long m2 = __ballot(b2);
    if ((lane & 31) == 0) {
      sgn[0][idx >> 5] = (unsigned)(m1 >> (lane & 32));
      sgn[1][idx >> 5] = (unsigned)(m2 >> (lane & 32));
    }
  }

  // Per-thread output-table quad, held in registers for all 4 iterations.
  const int o = tid * 4;
  const int4 pj = *(const int4*)(perm + o);
  int4 gi;
  gi.x = swz(pi_map(pi_map(pj.x)));
  gi.y = swz(pi_map(pi_map(pj.y)));
  gi.z = swz(pi_map(pi_map(pj.z)));
  gi.w = swz(pi_map(pi_map(pj.w)));
  float4 dg;
  dg.x = 0.0625f * INV2PI * D3[pj.x];
  dg.y = 0.0625f * INV2PI * D3[pj.y];
  dg.z = 0.0625f * INV2PI * D3[pj.z];
  dg.w = 0.0625f * INV2PI * D3[pj.w];
  float4 bz = *(const float4*)(bias + o);
  bz.x *= INV2PI; bz.y *= INV2PI; bz.z *= INV2PI; bz.w *= INV2PI;

  __syncthreads();  // signs visible + first DMA drained (vmcnt(0) at barrier)
  const unsigned sw1 = sgn[0][base >> 5] >> (base & 4);
  const unsigned sw2 = sgn[1][base >> 5] >> (base & 4);

  for (int it = 0; it < ITERS; ++it) {
    // ---- Stage 2: 16 elems/lane of row rr, fully in-register (in-place:
    //      each LDS position is read and written by exactly one thread).
    float r[16];
    float* L = &lds[rr][0];
#pragma unroll
    for (int g = 0; g < 4; ++g) {       // g bits -> p-bits {3,4}
      const int p = base | ((g & 1) << 3) | (((g >> 1) & 1) << 4);
      const float4 v = *(const float4*)(L + swz(p));
      r[g * 4 + 0] = v.x; r[g * 4 + 1] = v.y; r[g * 4 + 2] = v.z; r[g * 4 + 3] = v.w;
    }
    // D1 signs (input space), packed 1 word/lane.
#pragma unroll
    for (int e = 0; e < 16; ++e) {
      const int pos = (e & 3) | ((e & 12) << 1); // e0,e1->bits0,1; e2,e3->bits3,4
      r[e] = __int_as_float(__float_as_int(r[e]) ^ ((sw1 >> pos) << 31));
    }
    // fwht #1: Hadamard on p-bits {1,3,4,5}: e-bits {1,2,3} + lane-bit0
    bfly<2>(r); bfly<4>(r); bfly<8>(r);
    dpp_bfly<0xB1>(r, (l & 1) != 0);
    // D2 signs (z-space), packed 1 word/lane.
#pragma unroll
    for (int e = 0; e < 16; ++e) {
      const int pos = (e & 3) | ((e & 12) << 1);
      r[e] = __int_as_float(__float_as_int(r[e]) ^ ((sw2 >> pos) << 31));
    }
    // fwht #2: Hadamard on p-bits {0,3,4,8}: e-bits {0,2,3} + lane-bit1
    bfly<1>(r); bfly<4>(r); bfly<8>(r);
    dpp_bfly<0x4E>(r, (l & 2) != 0);
#pragma unroll
    for (int g = 0; g < 4; ++g) {
      const int p = base | ((g & 1) << 3) | (((g >> 1) & 1) << 4);
      const float4 v = make_float4(r[g * 4 + 0], r[g * 4 + 1], r[g * 4 + 2], r[g * 4 + 3]);
      *(float4*)(L + swz(p)) = v;
    }
    __syncthreads();

    // ---- Stage 3: permuted gather, cos epilogue, coalesced nt stores.
    const long row = row0 + (long)it * ROWS_PER_IT;
    float* op = out + row * NFEAT;
    floatx4 res0;
    res0.x = 0.03125f * __builtin_amdgcn_cosf(fmaf(lds[0][gi.x], dg.x, bz.x));
    res0.y = 0.03125f * __builtin_amdgcn_cosf(fmaf(lds[0][gi.y], dg.y, bz.y));
    res0.z = 0.03125f * __builtin_amdgcn_cosf(fmaf(lds[0][gi.z], dg.z, bz.z));
    res0.w = 0.03125f * __builtin_amdgcn_cosf(fmaf(lds[0][gi.w], dg.w, bz.w));
    __builtin_nontemporal_store(res0, (floatx4*)(op + o));
    floatx4 res1;
    res1.x = 0.03125f * __builtin_amdgcn_cosf(fmaf(lds[1][gi.x], dg.x, bz.x));
    res1.y = 0.03125f * __builtin_amdgcn_cosf(fmaf(lds[1][gi.y], dg.y, bz.y));
    res1.z = 0.03125f * __builtin_amdgcn_cosf(fmaf(lds[1][gi.z], dg.z, bz.z));
    res1.w = 0.03125f * __builtin_amdgcn_cosf(fmaf(lds[1][gi.w], dg.w, bz.w));
    __builtin_nontemporal_store(res1, (floatx4*)(op + NFEAT + o));

    // ---- Prefetch next row-pair (after all gathers of this pair done).
    if (it < ITERS - 1) {
      __syncthreads();                  // z fully consumed before overwrite
      const float* xn = x + (row + ROWS_PER_IT + rr) * HADN;
#pragma unroll
      for (int k = 0; k < 4; ++k) {
        const int p = (k * 256 + t256) * 4;
        gload_lds16(xn + swz(p), &lds[rr][p]);
      }
      __syncthreads();                  // DMA drained (vmcnt(0) at barrier)
    }
  }
}

extern "C" void kernel_launch(void* const* d_in, const int* in_sizes, int n_in,
                              void* d_out, int out_size, void* d_ws, size_t ws_size,
                              hipStream_t stream) {
  const float* x    = (const float*)d_in[0];
  const float* D1   = (const float*)d_in[1];
  const float* D2   = (const float*)d_in[2];
  const float* D3   = (const float*)d_in[3];
  const float* bias = (const float*)d_in[4];
  const int*   perm = (const int*)d_in[5];
  float* out = (float*)d_out;

  srf_all<<<8192 / (ROWS_PER_IT * ITERS), 512, 0, stream>>>(
      x, D1, D2, D3, perm, bias, out);
}

// Round 10
// 39.615 us; speedup vs baseline: 1.1272x; 1.1272x over previous
//
#include <hip/hip_runtime.h>

#define HADN 4096
#define NFEAT 2048
#define INV2PI 0.15915494309189535f

typedef float floatx4 __attribute__((ext_vector_type(4)));
typedef const __attribute__((address_space(1))) void* gas_cptr;
typedef __attribute__((address_space(3))) void* las_ptr;

// Async global->LDS DMA, 16B per lane. Address-space casts via integer
// round-trip. LDS dest must be wave-uniform base + lane*16 (ours is).
__device__ __forceinline__ void gload_lds16(const float* g, float* l) {
  __builtin_amdgcn_global_load_lds(
      (gas_cptr)(unsigned long long)g,
      (las_ptr)(unsigned)(unsigned long long)l, 16, 0, 0);
}

// out-bit <- in-axis mapping of one reference "fwht" (derived by axis tracking):
// bit0<-a6, bit1<-H(a3), bit2<-a7, bit3<-a0, bit4<-a8, bit5<-H(a4),
// bit6<-a9, bit7<-a2, bit8<-a10, bit9<-H(a5), bit10<-a11, bit11<-H(a1)
__device__ __forceinline__ int pi_map(int q) {
  return  (((q >> 3) & 1))
        | (((q >> 11) & 1) << 1)
        | (((q >> 7) & 1) << 2)
        | (((q >> 1) & 1) << 3)
        | (((q >> 5) & 1) << 4)
        | (((q >> 9) & 1) << 5)
        | (((q >> 0) & 1) << 6)
        | (((q >> 2) & 1) << 7)
        | (((q >> 4) & 1) << 8)
        | (((q >> 6) & 1) << 9)
        | (((q >> 8) & 1) << 10)
        | (((q >> 10) & 1) << 11);
}

__device__ __forceinline__ int pi_inv_map(int p) {
  return  (((p >> 6) & 1))
        | (((p >> 3) & 1) << 1)
        | (((p >> 7) & 1) << 2)
        | (((p >> 0) & 1) << 3)
        | (((p >> 8) & 1) << 4)
        | (((p >> 4) & 1) << 5)
        | (((p >> 9) & 1) << 6)
        | (((p >> 2) & 1) << 7)
        | (((p >> 10) & 1) << 8)
        | (((p >> 5) & 1) << 9)
        | (((p >> 11) & 1) << 10)
        | (((p >> 1) & 1) << 11);
}

// LDS bank swizzle: XOR bits {6,7,8}^{9,10,11} into bits {2,3,4}.
// Intra-128B-line permutation -> pre-swizzling the GLOBAL source keeps
// full-line coalescing per DMA instruction while LDS dest stays linear.
__device__ __forceinline__ int swz(int p) {
  return p ^ ((((p >> 6) ^ (p >> 9)) & 7) << 2);
}

template <int BIT>
__device__ __forceinline__ void bfly(float* r) {
#pragma unroll
  for (int e = 0; e < 16; ++e) {
    if ((e & BIT) == 0) {
      const int f = e | BIT;
      const float a = r[e], b = r[f];
      r[e] = a + b;
      r[f] = a - b;
    }
  }
}

// Cross-lane butterfly via DPP quad-perm (VALU, not DS pipe).
// CTRL=0xB1 -> lane^1, CTRL=0x4E -> lane^2.
template <int CTRL>
__device__ __forceinline__ void dpp_bfly(float* r, bool upper) {
  const unsigned sm = upper ? 0x80000000u : 0u;
#pragma unroll
  for (int e = 0; e < 16; ++e) {
    const int pv = __builtin_amdgcn_update_dpp(
        0, __float_as_int(r[e]), CTRL, 0xF, 0xF, true);
    r[e] = __int_as_float(pv) + __int_as_float(__float_as_int(r[e]) ^ sm);
  }
}

// Fully parallel setup: one thread per Hadamard index; sign packing via
// __ballot (64-bit mask; lanes 0 and 32 write the two 32-bit words).
__global__ __launch_bounds__(256) void srf_setup(
    const float* __restrict__ D1, const float* __restrict__ D2,
    const float* __restrict__ D3, const int* __restrict__ perm,
    const float* __restrict__ bias,
    unsigned* __restrict__ D1sgn, unsigned* __restrict__ D2sgn,
    float* __restrict__ dgc, int* __restrict__ gidx,
    float* __restrict__ bzc) {
  const int i = blockIdx.x * 256 + threadIdx.x;   // 0..4095 (16 blocks)
  const bool b1 = (__float_as_uint(D1[i]) >> 31) != 0;
  const bool b2 = (__float_as_uint(D2[pi_inv_map(i)]) >> 31) != 0;
  const unsigned long long m1 = __ballot(b1);
  const unsigned long long m2 = __ballot(b2);
  const int lane = i & 63;
  if ((lane & 31) == 0) {
    D1sgn[i >> 5] = (unsigned)(m1 >> (lane & 32));
    D2sgn[i >> 5] = (unsigned)(m2 >> (lane & 32));
  }
  if (i < NFEAT) {
    const int j = perm[i];
    gidx[i] = swz(pi_map(pi_map(j)));
    dgc[i] = 0.0625f * INV2PI * D3[j];
    bzc[i] = INV2PI * bias[i];
  }
}

// 512 threads, 2 rows per block. Wave-local DMA: each wave loads exactly the
// 1024-float region it consumes in stage 2 (p-bits {10,11} = wave id), so the
// first block barrier is replaced by a per-wave vmcnt(0) wait -> early waves
// compute while sibling waves' DMAs are still in flight.
__global__ __launch_bounds__(512) void srf_main(
    const float* __restrict__ x,
    const unsigned* __restrict__ D1sgn, const unsigned* __restrict__ D2sgn,
    const float* __restrict__ dgc, const int* __restrict__ gidx,
    const float* __restrict__ bzc, float* __restrict__ out) {
  __shared__ float lds[2][HADN];        // 32 KiB -> 4 blocks x 8 waves = 32 w/CU
  const int tid = threadIdx.x;
  const int rr = tid >> 8;              // which of the block's 2 rows
  const long row = (long)blockIdx.x * 2;
  const int l = tid & 63;
  const int w = (tid >> 6) & 3;         // wave-in-row -> p-bits {10,11}
  const int base = (((l >> 2) & 1) << 2) | ((l & 1) << 5) | (((l >> 3) & 1) << 6)
                 | (((l >> 4) & 1) << 7) | (((l >> 1) & 1) << 8)
                 | (((l >> 5) & 1) << 9) | (w << 10);

  // ---- Stage 1: async DMA x -> LDS, wave-local region, pre-swizzled source.
  //      LDS[rr][q] = x_row[swz(q)] for q in [w*1024, w*1024+1024).
  const float* xr = x + (row + rr) * HADN;
#pragma unroll
  for (int k = 0; k < 4; ++k) {
    const int q = w * 1024 + k * 256 + l * 4;  // linear dest float index
    gload_lds16(xr + swz(q), &lds[rr][q]);
  }

  // Sign words + stage-3 tables (global, L2-resident): issue now, they drain
  // with the same per-wave vmcnt wait.
  const unsigned sw1 = D1sgn[base >> 5] >> (base & 4);
  const unsigned sw2 = D2sgn[base >> 5] >> (base & 4);
  const int o = tid * 4;                // 512 threads x 4 = all 2048 outputs
  const int4   gi = *(const int4*)(gidx + o);
  const float4 dg = *(const float4*)(dgc + o);
  const float4 bz = *(const float4*)(bzc + o);

  // Per-wave wait: this wave's DMA + table loads done. No block barrier.
  asm volatile("s_waitcnt vmcnt(0)" ::: "memory");
  __builtin_amdgcn_sched_barrier(0);

  // ---- Stage 2: 16 elems/lane of row rr; p-bits {0,1,3,4} thread-local,
  //      p-bit5 on lane-bit0 (DPP xor1), p-bit8 on lane-bit1 (DPP xor2) ----
  float r[16];
  float* L = &lds[rr][0];
#pragma unroll
  for (int g = 0; g < 4; ++g) {         // g bits -> p-bits {3,4}
    const int p = base | ((g & 1) << 3) | (((g >> 1) & 1) << 4);
    const float4 v = *(const float4*)(L + swz(p));
    r[g * 4 + 0] = v.x; r[g * 4 + 1] = v.y; r[g * 4 + 2] = v.z; r[g * 4 + 3] = v.w;
  }
  // D1 signs (input space), packed 1 word/lane.
#pragma unroll
  for (int e = 0; e < 16; ++e) {
    const int pos = (e & 3) | ((e & 12) << 1);   // e0,e1->bits0,1; e2,e3->bits3,4
    r[e] = __int_as_float(__float_as_int(r[e]) ^ ((sw1 >> pos) << 31));
  }
  // fwht #1: Hadamard on p-bits {1,3,4,5}: e-bits {1,2,3} + lane-bit0
  bfly<2>(r); bfly<4>(r); bfly<8>(r);
  dpp_bfly<0xB1>(r, (l & 1) != 0);
  // D2 signs (z-space), packed 1 word/lane.
#pragma unroll
  for (int e = 0; e < 16; ++e) {
    const int pos = (e & 3) | ((e & 12) << 1);
    r[e] = __int_as_float(__float_as_int(r[e]) ^ ((sw2 >> pos) << 31));
  }
  // fwht #2: Hadamard on p-bits {0,3,4,8}: e-bits {0,2,3} + lane-bit1
  bfly<1>(r); bfly<4>(r); bfly<8>(r);
  dpp_bfly<0x4E>(r, (l & 2) != 0);

  // Single LDS write (swizzled -> balanced 8 lanes per 4-bank group).
#pragma unroll
  for (int g = 0; g < 4; ++g) {
    const int p = base | ((g & 1) << 3) | (((g >> 1) & 1) << 4);
    const float4 v = make_float4(r[g * 4 + 0], r[g * 4 + 1], r[g * 4 + 2], r[g * 4 + 3]);
    *(float4*)(L + swz(p)) = v;
  }
  __syncthreads();  // only barrier: stage-2 of all waves visible to gather

  // ---- Stage 3: permuted gather, cos epilogue, coalesced nt float4 store.
  //      Same o for both rows -> tables loaded once per block. ----
  float* op = out + row * NFEAT;
  floatx4 res0;
  res0.x = 0.03125f * __builtin_amdgcn_cosf(fmaf(lds[0][gi.x], dg.x, bz.x));
  res0.y = 0.03125f * __builtin_amdgcn_cosf(fmaf(lds[0][gi.y], dg.y, bz.y));
  res0.z = 0.03125f * __builtin_amdgcn_cosf(fmaf(lds[0][gi.z], dg.z, bz.z));
  res0.w = 0.03125f * __builtin_amdgcn_cosf(fmaf(lds[0][gi.w], dg.w, bz.w));
  __builtin_nontemporal_store(res0, (floatx4*)(op + o));
  floatx4 res1;
  res1.x = 0.03125f * __builtin_amdgcn_cosf(fmaf(lds[1][gi.x], dg.x, bz.x));
  res1.y = 0.03125f * __builtin_amdgcn_cosf(fmaf(lds[1][gi.y], dg.y, bz.y));
  res1.z = 0.03125f * __builtin_amdgcn_cosf(fmaf(lds[1][gi.z], dg.z, bz.z));
  res1.w = 0.03125f * __builtin_amdgcn_cosf(fmaf(lds[1][gi.w], dg.w, bz.w));
  __builtin_nontemporal_store(res1, (floatx4*)(op + NFEAT + o));
}

extern "C" void kernel_launch(void* const* d_in, const int* in_sizes, int n_in,
                              void* d_out, int out_size, void* d_ws, size_t ws_size,
                              hipStream_t stream) {
  const float* x    = (const float*)d_in[0];
  const float* D1   = (const float*)d_in[1];
  const float* D2   = (const float*)d_in[2];
  const float* D3   = (const float*)d_in[3];
  const float* bias = (const float*)d_in[4];
  const int*   perm = (const int*)d_in[5];
  float* out = (float*)d_out;

  unsigned* D1sgn = (unsigned*)d_ws;        // 128 u32
  unsigned* D2sgn = D1sgn + 128;            // 128 u32
  float*    dgc   = (float*)(D2sgn + 128);  // 2048 f32
  int*      gidx  = (int*)(dgc + NFEAT);    // 2048 i32
  float*    bzc   = (float*)(gidx + NFEAT); // 2048 f32

  srf_setup<<<16, 256, 0, stream>>>(D1, D2, D3, perm, bias,
                                    D1sgn, D2sgn, dgc, gidx, bzc);
  srf_main<<<4096, 512, 0, stream>>>(x, D1sgn, D2sgn, dgc, gidx, bzc, out);
}